// Round 7
// baseline (286.182 us; speedup 1.0000x reference)
//
#include <hip/hip_runtime.h>
#include <hip/hip_bf16.h>
#include <stdint.h>

using bf16 = __hip_bfloat16;
typedef short short8 __attribute__((ext_vector_type(8)));
typedef short short4v __attribute__((ext_vector_type(4)));
typedef float f32x4 __attribute__((ext_vector_type(4)));
typedef uint32_t u32x4 __attribute__((ext_vector_type(4)));

constexpr int N = 3072;
constexpr int D0 = 256;
constexpr int F1 = 128;
constexpr int F2 = 64;
constexpr int HEADS = 4;
constexpr int NW = N / 32;
constexpr float CSHIFT = 20.0f;   // softmax shift-invariance: fixed shift, no max pass

#define DI __device__ __forceinline__
DI short f2bs(float v) { bf16 b = __float2bfloat16(v); return *(short*)&b; }

// ---------------------------------------------------------------- pack adj
__global__ __launch_bounds__(256) void k_pack_adj(const int* __restrict__ adj,
                                                  uint32_t* __restrict__ bits) {
  int idx = blockIdx.x * 256 + threadIdx.x;
  unsigned long long m = __ballot(adj[idx] > 0);
  if ((threadIdx.x & 63) == 0) {
    bits[idx >> 5]       = (uint32_t)m;
    bits[(idx >> 5) + 1] = (uint32_t)(m >> 32);
  }
}

// ------------------------------------------------- convert params + x to bf16
__global__ __launch_bounds__(256) void k_cvt(const float* __restrict__ x,
                                             const float* __restrict__ W1,
                                             const float* __restrict__ lin1,
                                             const float* __restrict__ res1,
                                             const float* __restrict__ W2,
                                             const float* __restrict__ lin2,
                                             const float* __restrict__ res2,
                                             bf16* __restrict__ xb,
                                             bf16* __restrict__ W1T,
                                             bf16* __restrict__ lin1T,
                                             bf16* __restrict__ res1T,
                                             bf16* __restrict__ W2T,
                                             bf16* __restrict__ lin2T,
                                             bf16* __restrict__ res2T) {
  int t = blockIdx.y;
  int i = blockIdx.x * 256 + threadIdx.x;
  switch (t) {
    case 0:
      if (i < N * D0) xb[i] = __float2bfloat16(x[i]);
      break;
    case 1:
      if (i < HEADS * F1 * D0) { int k = i & 255; int ho = i >> 8; int h = ho >> 7, o = ho & 127;
        W1T[i] = __float2bfloat16(W1[((size_t)h * D0 + k) * F1 + o]); }
      break;
    case 2:
      if (i < F1 * HEADS * F1) { int k = i & 511; int o = i >> 9;
        lin1T[i] = __float2bfloat16(lin1[k * F1 + o]); }
      break;
    case 3:
      if (i < F1 * D0) { int k = i & 255; int o = i >> 8;
        res1T[i] = __float2bfloat16(res1[k * F1 + o]); }
      break;
    case 4:
      if (i < HEADS * F2 * F1) { int k = i & 127; int ho = i >> 7; int h = ho >> 6, o = ho & 63;
        W2T[i] = __float2bfloat16(W2[((size_t)h * F1 + k) * F2 + o]); }
      break;
    case 5:
      if (i < F2 * HEADS * F2) { int k = i & 255; int o = i >> 8;
        lin2T[i] = __float2bfloat16(lin2[k * F2 + o]); }
      break;
    case 6:
      if (i < F2 * F1) { int k = i & 127; int o = i >> 7;
        res2T[i] = __float2bfloat16(res2[k * F2 + o]); }
      break;
  }
}

// ------------------------------------------------- projection GEMM (MFMA)
// WhT[col][row] = sum_k A[row][k] * BT[col][k]
template <int K, int NOUT>
__global__ __launch_bounds__(256) void k_whead_mfma(const bf16* __restrict__ A,
                                                    const bf16* __restrict__ BT,
                                                    bf16* __restrict__ WhT) {
  int n0 = blockIdx.x * 64;
  int c0 = blockIdx.y * 64;
  int wid = threadIdx.x >> 6, lane = threadIdx.x & 63;
  int l15 = lane & 15, q = lane >> 4;
  int row0 = n0 + wid * 16;
  const bf16* aP = A + (size_t)(row0 + l15) * K + q * 8;
  f32x4 acc[4];
#pragma unroll
  for (int ct = 0; ct < 4; ct++)
#pragma unroll
    for (int r = 0; r < 4; r++) acc[ct][r] = 0.f;
  for (int ks = 0; ks < K / 32; ks++) {
    short8 a = *(const short8*)(aP + ks * 32);
#pragma unroll
    for (int ct = 0; ct < 4; ct++) {
      short8 b = *(const short8*)(BT + (size_t)(c0 + ct * 16 + l15) * K + q * 8 + ks * 32);
      acc[ct] = __builtin_amdgcn_mfma_f32_16x16x32_bf16(a, b, acc[ct], 0, 0, 0);
    }
  }
#pragma unroll
  for (int ct = 0; ct < 4; ct++) {
    int col = c0 + ct * 16 + l15;
    short4v w;
#pragma unroll
    for (int r = 0; r < 4; r++) w[r] = f2bs(acc[ct][r]);
    *(short4v*)(WhT + (size_t)col * N + row0 + q * 4) = w;
  }
}

// ---------------------------------------------------------- src/dst from WhT
template <int F>
__global__ __launch_bounds__(256) void k_srcdst(const bf16* __restrict__ WhT,
                                                const float* __restrict__ as_,
                                                const float* __restrict__ ad_,
                                                float* __restrict__ src,
                                                float* __restrict__ dst) {
  int h = blockIdx.y;
  int n = blockIdx.x * 256 + threadIdx.x;
  float s = 0.f, d = 0.f;
  for (int o = 0; o < F; o++) {
    float w = __bfloat162float(WhT[(size_t)(h * F + o) * N + n]);
    s += w * as_[h * F + o];
    d += w * ad_[h * F + o];
  }
  src[h * N + n] = s;
  dst[h * N + n] = d;
}

// ---------------- fused attention, LDS-staged B with XOR swizzle
// block = 64 rows x 1 head, 4 waves x 16 rows, full K per wave (no cross-wave red)
// hp[i][h*F+o] = elu( (sum_j P_ij WhT[o][j]) / sum_j P_ij )
template <int F>
__global__ __launch_bounds__(256) void k_attn_fused(const bf16* __restrict__ WhT,
                                                    const float* __restrict__ src,
                                                    const float* __restrict__ dst,
                                                    const uint32_t* __restrict__ bits,
                                                    bf16* __restrict__ hp) {
  constexpr int CT = F / 16;             // 8 (F1) / 4 (F2)
  constexpr int JT = 128;                // j per tile
  constexpr int NT = N / JT;             // 24 tiles
  constexpr int STG = F * JT * 2 / (256 * 16);   // 16B chunks/thread: 8 / 4
  int h   = blockIdx.y;
  int i0  = blockIdx.x * 64;
  int tid = threadIdx.x, wid = tid >> 6, lane = tid & 63;
  int l15 = lane & 15, q = lane >> 4;
  int row = i0 + wid * 16 + l15;

  __shared__ float sDst[N];                          // 12 KB broadcast
  __shared__ __align__(16) char sB[2][F * JT * 2];   // 2 x 32/16 KB swizzled tiles

  for (int t = tid; t < N; t += 256) sDst[t] = dst[h * N + t];
  float srcr = src[h * N + row];
  const uint32_t* brow = bits + (size_t)row * NW;

  // staging geometry: flat 16B chunk c covers col = fb>>8, jb = (fb&255)>>4
  const bf16* gsrc[STG];
  int ldst[STG];
#pragma unroll
  for (int c = 0; c < STG; c++) {
    int fb  = c * 4096 + tid * 16;
    int col = fb >> 8, jb = (fb & 255) >> 4;
    gsrc[c] = WhT + (size_t)(h * F + col) * N + jb * 8;
    ldst[c] = col * 256 + ((jb * 16) ^ ((col & 15) << 4));   // XOR-swizzled dest
  }

  f32x4 acc[CT];
#pragma unroll
  for (int ct = 0; ct < CT; ct++)
#pragma unroll
    for (int r = 0; r < 4; r++) acc[ct][r] = 0.f;
  float rowsum = 0.f;

  short8 rg[STG];
  // prologue: tile 0
#pragma unroll
  for (int c = 0; c < STG; c++) rg[c] = *(const short8*)(gsrc[c]);
#pragma unroll
  for (int c = 0; c < STG; c++) *(short8*)(&sB[0][ldst[c]]) = rg[c];

  for (int t = 0; t < NT; t++) {
    __syncthreads();                       // buf[t&1] staged & prior reads done
    if (t + 1 < NT) {
#pragma unroll
      for (int c = 0; c < STG; c++) rg[c] = *(const short8*)(gsrc[c] + (size_t)(t + 1) * JT);
    }
    // ---- compute tile t from sB[t&1]
    u32x4 wds = *(const u32x4*)(brow + t * 4);
    const char* bb = sB[t & 1];
#pragma unroll
    for (int ks = 0; ks < 4; ks++) {
      const f32x4* dp = (const f32x4*)(&sDst[t * JT + ks * 32 + q * 8]);
      f32x4 dlo = dp[0], dhi = dp[1];
      uint32_t myb = (wds[ks] >> (q * 8)) & 0xffu;
      float pv[8];
#pragma unroll
      for (int e = 0; e < 8; e++) {
        float tv = srcr + (e < 4 ? dlo[e] : dhi[e - 4]);
        tv = tv > 0.f ? tv : 0.2f * tv;
        float pe = ((myb >> e) & 1u) ? __expf(tv - CSHIFT) : 0.f;
        rowsum += pe;
        pv[e] = pe;
      }
      short8 a;
#pragma unroll
      for (int e = 0; e < 8; e++) a[e] = f2bs(pv[e]);
#pragma unroll
      for (int ct = 0; ct < CT; ct++) {
        int col = ct * 16 + l15;
        short8 b = *(const short8*)(bb + col * 256 + (((ks * 4 + q) << 4) ^ (l15 << 4)));
        acc[ct] = __builtin_amdgcn_mfma_f32_16x16x32_bf16(a, b, acc[ct], 0, 0, 0);
      }
    }
    __syncthreads();                       // all waves done reading buf[t&1]
    if (t + 1 < NT) {
#pragma unroll
      for (int c = 0; c < STG; c++) *(short8*)(&sB[(t + 1) & 1][ldst[c]]) = rg[c];
    }
  }

  // row sums: q-slices combine within wave
  rowsum += __shfl_xor(rowsum, 16);
  rowsum += __shfl_xor(rowsum, 32);

#pragma unroll
  for (int ct = 0; ct < CT; ct++)
#pragma unroll
    for (int r = 0; r < 4; r++) {
      float rs = __shfl(rowsum, q * 4 + r);          // lane q*4+r holds that row's sum
      float v  = acc[ct][r] / rs;
      v = v > 0.f ? v : __expf(v) - 1.f;             // elu
      int gi = i0 + wid * 16 + q * 4 + r;
      hp[(size_t)gi * (HEADS * F) + h * F + ct * 16 + l15] = __float2bfloat16(v);
    }
}

// ------------------------------ mix GEMM (MFMA): out = relu(elu(A1@B1) + A2@B2)
template <int K1, int K2, int NOUT, bool F32OUT>
__global__ __launch_bounds__(256) void k_mix_mfma(const bf16* __restrict__ A1,
                                                  const bf16* __restrict__ B1T,
                                                  const bf16* __restrict__ A2,
                                                  const bf16* __restrict__ B2T,
                                                  void* __restrict__ outv) {
  int n0 = blockIdx.x * 64;
  int c0 = blockIdx.y * 64;
  int wid = threadIdx.x >> 6, lane = threadIdx.x & 63;
  int l15 = lane & 15, q = lane >> 4;
  int row0 = n0 + wid * 16;

  f32x4 acc1[4], acc2[4];
#pragma unroll
  for (int ct = 0; ct < 4; ct++)
#pragma unroll
    for (int r = 0; r < 4; r++) { acc1[ct][r] = 0.f; acc2[ct][r] = 0.f; }

  const bf16* a1P = A1 + (size_t)(row0 + l15) * K1 + q * 8;
  for (int ks = 0; ks < K1 / 32; ks++) {
    short8 a = *(const short8*)(a1P + ks * 32);
#pragma unroll
    for (int ct = 0; ct < 4; ct++) {
      short8 b = *(const short8*)(B1T + (size_t)(c0 + ct * 16 + l15) * K1 + q * 8 + ks * 32);
      acc1[ct] = __builtin_amdgcn_mfma_f32_16x16x32_bf16(a, b, acc1[ct], 0, 0, 0);
    }
  }
  const bf16* a2P = A2 + (size_t)(row0 + l15) * K2 + q * 8;
  for (int ks = 0; ks < K2 / 32; ks++) {
    short8 a = *(const short8*)(a2P + ks * 32);
#pragma unroll
    for (int ct = 0; ct < 4; ct++) {
      short8 b = *(const short8*)(B2T + (size_t)(c0 + ct * 16 + l15) * K2 + q * 8 + ks * 32);
      acc2[ct] = __builtin_amdgcn_mfma_f32_16x16x32_bf16(a, b, acc2[ct], 0, 0, 0);
    }
  }

#pragma unroll
  for (int ct = 0; ct < 4; ct++) {
    int col = c0 + ct * 16 + l15;
#pragma unroll
    for (int r = 0; r < 4; r++) {
      float v = acc1[ct][r];
      v = v > 0.f ? v : __expf(v) - 1.f;         // elu on A1@B1
      v += acc2[ct][r];
      v = v > 0.f ? v : 0.f;                     // relu
      int row = row0 + q * 4 + r;
      if (F32OUT) ((float*)outv)[(size_t)row * NOUT + col] = v;
      else        ((bf16*)outv)[(size_t)row * NOUT + col] = __float2bfloat16(v);
    }
  }
}

// ---------------------------------------------------------------- launcher
extern "C" void kernel_launch(void* const* d_in, const int* in_sizes, int n_in,
                              void* d_out, int out_size, void* d_ws, size_t ws_size,
                              hipStream_t stream) {
  const float* x    = (const float*)d_in[0];
  const int*   adj  = (const int*)d_in[1];
  const float* W1   = (const float*)d_in[2];
  const float* a1s  = (const float*)d_in[3];
  const float* a1d  = (const float*)d_in[4];
  const float* lin1 = (const float*)d_in[5];
  const float* res1 = (const float*)d_in[6];
  const float* W2   = (const float*)d_in[7];
  const float* a2s  = (const float*)d_in[8];
  const float* a2d  = (const float*)d_in[9];
  const float* lin2 = (const float*)d_in[10];
  const float* res2 = (const float*)d_in[11];
  float* out = (float*)d_out;

  char* p = (char*)d_ws;
  auto alloc = [&](size_t bytes) { void* r = (void*)p; p += (bytes + 255) & ~(size_t)255; return r; };
  uint32_t* bits = (uint32_t*)alloc((size_t)N * NW * 4);
  bf16* xb    = (bf16*)alloc((size_t)N * D0 * 2);
  bf16* W1T   = (bf16*)alloc((size_t)HEADS * F1 * D0 * 2);
  bf16* lin1T = (bf16*)alloc((size_t)F1 * HEADS * F1 * 2);
  bf16* res1T = (bf16*)alloc((size_t)F1 * D0 * 2);
  bf16* W2T   = (bf16*)alloc((size_t)HEADS * F2 * F1 * 2);
  bf16* lin2T = (bf16*)alloc((size_t)F2 * HEADS * F2 * 2);
  bf16* res2T = (bf16*)alloc((size_t)F2 * F1 * 2);
  bf16* WhT1  = (bf16*)alloc((size_t)HEADS * F1 * N * 2);
  bf16* WhT2  = (bf16*)alloc((size_t)HEADS * F2 * N * 2);
  float* src1 = (float*)alloc((size_t)HEADS * N * 4);
  float* dst1 = (float*)alloc((size_t)HEADS * N * 4);
  float* src2 = (float*)alloc((size_t)HEADS * N * 4);
  float* dst2 = (float*)alloc((size_t)HEADS * N * 4);
  bf16* hp1   = (bf16*)alloc((size_t)N * HEADS * F1 * 2);
  bf16* hp2   = (bf16*)alloc((size_t)N * HEADS * F2 * 2);
  bf16* h1b   = (bf16*)alloc((size_t)N * F1 * 2);

  k_pack_adj<<<dim3(N * N / 256), dim3(256), 0, stream>>>(adj, bits);
  k_cvt<<<dim3(N * D0 / 256, 7), dim3(256), 0, stream>>>(x, W1, lin1, res1, W2, lin2, res2,
                                                         xb, W1T, lin1T, res1T, W2T, lin2T, res2T);

  // layer 1
  k_whead_mfma<D0, HEADS * F1><<<dim3(N / 64, HEADS * F1 / 64), dim3(256), 0, stream>>>(xb, W1T, WhT1);
  k_srcdst<F1><<<dim3(N / 256, HEADS), dim3(256), 0, stream>>>(WhT1, a1s, a1d, src1, dst1);
  k_attn_fused<F1><<<dim3(N / 64, HEADS), dim3(256), 0, stream>>>(WhT1, src1, dst1, bits, hp1);
  k_mix_mfma<HEADS * F1, D0, F1, false>
      <<<dim3(N / 64, F1 / 64), dim3(256), 0, stream>>>(hp1, lin1T, xb, res1T, h1b);

  // layer 2
  k_whead_mfma<F1, HEADS * F2><<<dim3(N / 64, HEADS * F2 / 64), dim3(256), 0, stream>>>(h1b, W2T, WhT2);
  k_srcdst<F2><<<dim3(N / 256, HEADS), dim3(256), 0, stream>>>(WhT2, a2s, a2d, src2, dst2);
  k_attn_fused<F2><<<dim3(N / 64, HEADS), dim3(256), 0, stream>>>(WhT2, src2, dst2, bits, hp2);
  k_mix_mfma<HEADS * F2, F1, F2, true>
      <<<dim3(N / 64, F2 / 64), dim3(256), 0, stream>>>(hp2, lin2T, h1b, res2T, out);
}

// Round 8
// 261.057 us; speedup vs baseline: 1.0962x; 1.0962x over previous
//
#include <hip/hip_runtime.h>
#include <hip/hip_bf16.h>
#include <stdint.h>

using bf16 = __hip_bfloat16;
typedef short short8 __attribute__((ext_vector_type(8)));
typedef short short4v __attribute__((ext_vector_type(4)));
typedef float f32x4 __attribute__((ext_vector_type(4)));
typedef uint32_t u32x4 __attribute__((ext_vector_type(4)));

constexpr int N = 3072;
constexpr int D0 = 256;
constexpr int F1 = 128;
constexpr int F2 = 64;
constexpr int HEADS = 4;
constexpr int NW = N / 32;
constexpr float CSHIFT = 20.0f;   // softmax shift-invariance: fixed shift, no max pass

#define DI __device__ __forceinline__
DI short f2bs(float v) { bf16 b = __float2bfloat16(v); return *(short*)&b; }

// ---------------------------------------------------------------- pack adj
__global__ __launch_bounds__(256) void k_pack_adj(const int* __restrict__ adj,
                                                  uint32_t* __restrict__ bits) {
  int idx = blockIdx.x * 256 + threadIdx.x;
  unsigned long long m = __ballot(adj[idx] > 0);
  if ((threadIdx.x & 63) == 0) {
    bits[idx >> 5]       = (uint32_t)m;
    bits[(idx >> 5) + 1] = (uint32_t)(m >> 32);
  }
}

// ------------------------------------------------- convert params + x to bf16
__global__ __launch_bounds__(256) void k_cvt(const float* __restrict__ x,
                                             const float* __restrict__ W1,
                                             const float* __restrict__ lin1,
                                             const float* __restrict__ res1,
                                             const float* __restrict__ W2,
                                             const float* __restrict__ lin2,
                                             const float* __restrict__ res2,
                                             bf16* __restrict__ xb,
                                             bf16* __restrict__ W1T,
                                             bf16* __restrict__ lin1T,
                                             bf16* __restrict__ res1T,
                                             bf16* __restrict__ W2T,
                                             bf16* __restrict__ lin2T,
                                             bf16* __restrict__ res2T) {
  int t = blockIdx.y;
  int i = blockIdx.x * 256 + threadIdx.x;
  switch (t) {
    case 0:
      if (i < N * D0) xb[i] = __float2bfloat16(x[i]);
      break;
    case 1:
      if (i < HEADS * F1 * D0) { int k = i & 255; int ho = i >> 8; int h = ho >> 7, o = ho & 127;
        W1T[i] = __float2bfloat16(W1[((size_t)h * D0 + k) * F1 + o]); }
      break;
    case 2:
      if (i < F1 * HEADS * F1) { int k = i & 511; int o = i >> 9;
        lin1T[i] = __float2bfloat16(lin1[k * F1 + o]); }
      break;
    case 3:
      if (i < F1 * D0) { int k = i & 255; int o = i >> 8;
        res1T[i] = __float2bfloat16(res1[k * F1 + o]); }
      break;
    case 4:
      if (i < HEADS * F2 * F1) { int k = i & 127; int ho = i >> 7; int h = ho >> 6, o = ho & 63;
        W2T[i] = __float2bfloat16(W2[((size_t)h * F1 + k) * F2 + o]); }
      break;
    case 5:
      if (i < F2 * HEADS * F2) { int k = i & 255; int o = i >> 8;
        lin2T[i] = __float2bfloat16(lin2[k * F2 + o]); }
      break;
    case 6:
      if (i < F2 * F1) { int k = i & 127; int o = i >> 7;
        res2T[i] = __float2bfloat16(res2[k * F2 + o]); }
      break;
  }
}

// ------------------------------------------------- projection GEMM (MFMA), 16-row blocks
// WhT[col][row] = sum_k A[row][k]*BT[col][k]; epilogue fuses src/dst partial GEMV
// grid (N/16, NOUT/64); wave wid handles cols c0+wid*16..+16
template <int K, int NOUT, int F>
__global__ __launch_bounds__(256) void k_whead_mfma(const bf16* __restrict__ A,
                                                    const bf16* __restrict__ BT,
                                                    bf16* __restrict__ WhT,
                                                    const float* __restrict__ as_,
                                                    const float* __restrict__ ad_,
                                                    float* __restrict__ src,
                                                    float* __restrict__ dst) {
  int row0 = blockIdx.x * 16;
  int wid = threadIdx.x >> 6, lane = threadIdx.x & 63;
  int l15 = lane & 15, q = lane >> 4;
  int col = blockIdx.y * 64 + wid * 16 + l15;

  const bf16* aP = A + (size_t)(row0 + l15) * K + q * 8;
  const bf16* bP = BT + (size_t)col * K + q * 8;
  f32x4 acc;
#pragma unroll
  for (int r = 0; r < 4; r++) acc[r] = 0.f;
#pragma unroll
  for (int ks = 0; ks < K / 32; ks++) {
    short8 a = *(const short8*)(aP + ks * 32);
    short8 b = *(const short8*)(bP + ks * 32);
    acc = __builtin_amdgcn_mfma_f32_16x16x32_bf16(a, b, acc, 0, 0, 0);
  }

  short4v w;
#pragma unroll
  for (int r = 0; r < 4; r++) w[r] = f2bs(acc[r]);
  *(short4v*)(WhT + (size_t)col * N + row0 + q * 4) = w;

  int h = col / F;
  float asv = as_[col], adv = ad_[col];
#pragma unroll
  for (int r = 0; r < 4; r++) {
    float sp = acc[r] * asv, dp = acc[r] * adv;
#pragma unroll
    for (int m = 1; m < 16; m <<= 1) {
      sp += __shfl_xor(sp, m);
      dp += __shfl_xor(dp, m);
    }
    if (l15 == 0) {
      atomicAdd(&src[h * N + row0 + q * 4 + r], sp);
      atomicAdd(&dst[h * N + row0 + q * 4 + r], dp);
    }
  }
}

// ---------------- fused attention, LDS-staged B (XOR swizzle), col-split
// block: 64 rows x (F/CSPLIT) cols of one head; 4 waves x 16 rows, full K
template <int F, int CSPLIT>
__global__ __launch_bounds__(256) void k_attn_fused(const bf16* __restrict__ WhT,
                                                    const float* __restrict__ src,
                                                    const float* __restrict__ dst,
                                                    const uint32_t* __restrict__ bits,
                                                    bf16* __restrict__ hp) {
  constexpr int FL = F / CSPLIT;         // cols this block owns: 64 / 32
  constexpr int CT = FL / 16;            // 4 / 2
  constexpr int JT = 128;
  constexpr int NT = N / JT;             // 24
  constexpr int STG = FL * JT * 2 / (256 * 16);   // 16B chunks/thread: 4 / 2
  int h   = blockIdx.y / CSPLIT;
  int cs  = blockIdx.y % CSPLIT;
  int cb  = h * F + cs * FL;             // WhT col base
  int i0  = blockIdx.x * 64;
  int tid = threadIdx.x, wid = tid >> 6, lane = tid & 63;
  int l15 = lane & 15, q = lane >> 4;
  int row = i0 + wid * 16 + l15;

  __shared__ float sDst[N];                          // 12 KB broadcast
  __shared__ __align__(16) char sB[2][FL * JT * 2];  // swizzled tiles

  for (int t = tid; t < N; t += 256) sDst[t] = dst[h * N + t];
  float srcr = src[h * N + row];
  const uint32_t* brow = bits + (size_t)row * NW;

  const bf16* gsrc[STG];
  int ldst[STG];
#pragma unroll
  for (int c = 0; c < STG; c++) {
    int fb  = c * 4096 + tid * 16;
    int col = fb >> 8, jb = (fb & 255) >> 4;
    gsrc[c] = WhT + (size_t)(cb + col) * N + jb * 8;
    ldst[c] = col * 256 + ((jb * 16) ^ ((col & 15) << 4));
  }

  f32x4 acc[CT];
#pragma unroll
  for (int ct = 0; ct < CT; ct++)
#pragma unroll
    for (int r = 0; r < 4; r++) acc[ct][r] = 0.f;
  float rowsum = 0.f;

  short8 rg[STG];
#pragma unroll
  for (int c = 0; c < STG; c++) rg[c] = *(const short8*)(gsrc[c]);
#pragma unroll
  for (int c = 0; c < STG; c++) *(short8*)(&sB[0][ldst[c]]) = rg[c];

  for (int t = 0; t < NT; t++) {
    __syncthreads();
    if (t + 1 < NT) {
#pragma unroll
      for (int c = 0; c < STG; c++) rg[c] = *(const short8*)(gsrc[c] + (size_t)(t + 1) * JT);
    }
    u32x4 wds = *(const u32x4*)(brow + t * 4);
    const char* bb = sB[t & 1];
#pragma unroll
    for (int ks = 0; ks < 4; ks++) {
      const f32x4* dp = (const f32x4*)(&sDst[t * JT + ks * 32 + q * 8]);
      f32x4 dlo = dp[0], dhi = dp[1];
      uint32_t myb = (wds[ks] >> (q * 8)) & 0xffu;
      float pv[8];
#pragma unroll
      for (int e = 0; e < 8; e++) {
        float tv = srcr + (e < 4 ? dlo[e] : dhi[e - 4]);
        tv = tv > 0.f ? tv : 0.2f * tv;
        float pe = ((myb >> e) & 1u) ? __expf(tv - CSHIFT) : 0.f;
        rowsum += pe;
        pv[e] = pe;
      }
      short8 a;
#pragma unroll
      for (int e = 0; e < 8; e++) a[e] = f2bs(pv[e]);
#pragma unroll
      for (int ct = 0; ct < CT; ct++) {
        int col = ct * 16 + l15;
        short8 b = *(const short8*)(bb + col * 256 + (((ks * 4 + q) << 4) ^ (l15 << 4)));
        acc[ct] = __builtin_amdgcn_mfma_f32_16x16x32_bf16(a, b, acc[ct], 0, 0, 0);
      }
    }
    __syncthreads();
    if (t + 1 < NT) {
#pragma unroll
      for (int c = 0; c < STG; c++) *(short8*)(&sB[(t + 1) & 1][ldst[c]]) = rg[c];
    }
  }

  rowsum += __shfl_xor(rowsum, 16);
  rowsum += __shfl_xor(rowsum, 32);

#pragma unroll
  for (int ct = 0; ct < CT; ct++)
#pragma unroll
    for (int r = 0; r < 4; r++) {
      float rs = __shfl(rowsum, q * 4 + r);
      float v  = acc[ct][r] / rs;
      v = v > 0.f ? v : __expf(v) - 1.f;             // elu
      int gi = i0 + wid * 16 + q * 4 + r;
      hp[(size_t)gi * (HEADS * F) + h * F + cs * FL + ct * 16 + l15] = __float2bfloat16(v);
    }
}

// ------------------ mix GEMM (MFMA), 16-row blocks: out = relu(elu(A1@B1)+A2@B2)
// grid (N/16, NOUT/64); wave wid handles cols c0+wid*16..+16, full K
template <int K1, int K2, int NOUT, bool F32OUT>
__global__ __launch_bounds__(256) void k_mix_mfma(const bf16* __restrict__ A1,
                                                  const bf16* __restrict__ B1T,
                                                  const bf16* __restrict__ A2,
                                                  const bf16* __restrict__ B2T,
                                                  void* __restrict__ outv) {
  int row0 = blockIdx.x * 16;
  int wid = threadIdx.x >> 6, lane = threadIdx.x & 63;
  int l15 = lane & 15, q = lane >> 4;
  int col = blockIdx.y * 64 + wid * 16 + l15;

  f32x4 acc1, acc2;
#pragma unroll
  for (int r = 0; r < 4; r++) { acc1[r] = 0.f; acc2[r] = 0.f; }

  const bf16* a1P = A1 + (size_t)(row0 + l15) * K1 + q * 8;
  const bf16* b1P = B1T + (size_t)col * K1 + q * 8;
#pragma unroll
  for (int ks = 0; ks < K1 / 32; ks++) {
    short8 a = *(const short8*)(a1P + ks * 32);
    short8 b = *(const short8*)(b1P + ks * 32);
    acc1 = __builtin_amdgcn_mfma_f32_16x16x32_bf16(a, b, acc1, 0, 0, 0);
  }
  const bf16* a2P = A2 + (size_t)(row0 + l15) * K2 + q * 8;
  const bf16* b2P = B2T + (size_t)col * K2 + q * 8;
#pragma unroll
  for (int ks = 0; ks < K2 / 32; ks++) {
    short8 a = *(const short8*)(a2P + ks * 32);
    short8 b = *(const short8*)(b2P + ks * 32);
    acc2 = __builtin_amdgcn_mfma_f32_16x16x32_bf16(a, b, acc2, 0, 0, 0);
  }

#pragma unroll
  for (int r = 0; r < 4; r++) {
    float v = acc1[r];
    v = v > 0.f ? v : __expf(v) - 1.f;         // elu on A1@B1
    v += acc2[r];
    v = v > 0.f ? v : 0.f;                     // relu
    int rw = row0 + q * 4 + r;
    if (F32OUT) ((float*)outv)[(size_t)rw * NOUT + col] = v;
    else        ((bf16*)outv)[(size_t)rw * NOUT + col] = __float2bfloat16(v);
  }
}

// ---------------------------------------------------------------- launcher
extern "C" void kernel_launch(void* const* d_in, const int* in_sizes, int n_in,
                              void* d_out, int out_size, void* d_ws, size_t ws_size,
                              hipStream_t stream) {
  const float* x    = (const float*)d_in[0];
  const int*   adj  = (const int*)d_in[1];
  const float* W1   = (const float*)d_in[2];
  const float* a1s  = (const float*)d_in[3];
  const float* a1d  = (const float*)d_in[4];
  const float* lin1 = (const float*)d_in[5];
  const float* res1 = (const float*)d_in[6];
  const float* W2   = (const float*)d_in[7];
  const float* a2s  = (const float*)d_in[8];
  const float* a2d  = (const float*)d_in[9];
  const float* lin2 = (const float*)d_in[10];
  const float* res2 = (const float*)d_in[11];
  float* out = (float*)d_out;

  char* p = (char*)d_ws;
  auto alloc = [&](size_t bytes) { void* r = (void*)p; p += (bytes + 255) & ~(size_t)255; return r; };
  uint32_t* bits = (uint32_t*)alloc((size_t)N * NW * 4);
  bf16* xb    = (bf16*)alloc((size_t)N * D0 * 2);
  bf16* W1T   = (bf16*)alloc((size_t)HEADS * F1 * D0 * 2);
  bf16* lin1T = (bf16*)alloc((size_t)F1 * HEADS * F1 * 2);
  bf16* res1T = (bf16*)alloc((size_t)F1 * D0 * 2);
  bf16* W2T   = (bf16*)alloc((size_t)HEADS * F2 * F1 * 2);
  bf16* lin2T = (bf16*)alloc((size_t)F2 * HEADS * F2 * 2);
  bf16* res2T = (bf16*)alloc((size_t)F2 * F1 * 2);
  bf16* WhT1  = (bf16*)alloc((size_t)HEADS * F1 * N * 2);
  bf16* WhT2  = (bf16*)alloc((size_t)HEADS * F2 * N * 2);
  float* src1 = (float*)alloc((size_t)HEADS * N * 4);   // these four contiguous
  float* dst1 = (float*)alloc((size_t)HEADS * N * 4);
  float* src2 = (float*)alloc((size_t)HEADS * N * 4);
  float* dst2 = (float*)alloc((size_t)HEADS * N * 4);
  bf16* hp1   = (bf16*)alloc((size_t)N * HEADS * F1 * 2);
  bf16* hp2   = (bf16*)alloc((size_t)N * HEADS * F2 * 2);
  bf16* h1b   = (bf16*)alloc((size_t)N * F1 * 2);

  hipMemsetAsync(src1, 0, (size_t)HEADS * N * 4 * 4, stream);  // src1,dst1,src2,dst2

  k_pack_adj<<<dim3(N * N / 256), dim3(256), 0, stream>>>(adj, bits);
  k_cvt<<<dim3(N * D0 / 256, 7), dim3(256), 0, stream>>>(x, W1, lin1, res1, W2, lin2, res2,
                                                         xb, W1T, lin1T, res1T, W2T, lin2T, res2T);

  // layer 1
  k_whead_mfma<D0, HEADS * F1, F1>
      <<<dim3(N / 16, HEADS * F1 / 64), dim3(256), 0, stream>>>(xb, W1T, WhT1, a1s, a1d, src1, dst1);
  k_attn_fused<F1, 2><<<dim3(N / 64, HEADS * 2), dim3(256), 0, stream>>>(WhT1, src1, dst1, bits, hp1);
  k_mix_mfma<HEADS * F1, D0, F1, false>
      <<<dim3(N / 16, F1 / 64), dim3(256), 0, stream>>>(hp1, lin1T, xb, res1T, h1b);

  // layer 2
  k_whead_mfma<F1, HEADS * F2, F2>
      <<<dim3(N / 16, HEADS * F2 / 64), dim3(256), 0, stream>>>(h1b, W2T, WhT2, a2s, a2d, src2, dst2);
  k_attn_fused<F2, 2><<<dim3(N / 64, HEADS * 2), dim3(256), 0, stream>>>(WhT2, src2, dst2, bits, hp2);
  k_mix_mfma<HEADS * F2, F1, F2, true>
      <<<dim3(N / 16, F2 / 64), dim3(256), 0, stream>>>(hp2, lin2T, h1b, res2T, out);
}

// Round 9
// 208.944 us; speedup vs baseline: 1.3697x; 1.2494x over previous
//
#include <hip/hip_runtime.h>
#include <hip/hip_bf16.h>
#include <stdint.h>

using bf16 = __hip_bfloat16;
typedef short short8 __attribute__((ext_vector_type(8)));
typedef short short4v __attribute__((ext_vector_type(4)));
typedef float f32x4 __attribute__((ext_vector_type(4)));

constexpr int N = 3072;
constexpr int D0 = 256;
constexpr int F1 = 128;
constexpr int F2 = 64;
constexpr int HEADS = 4;
constexpr int NW = N / 32;
constexpr float CSHIFT = 20.0f;   // softmax shift-invariance: fixed shift, no max pass

#define DI __device__ __forceinline__
DI short f2bs(float v) { bf16 b = __float2bfloat16(v); return *(short*)&b; }

// ---------------------------------------------------------------- pack adj
__global__ __launch_bounds__(256) void k_pack_adj(const int* __restrict__ adj,
                                                  uint32_t* __restrict__ bits) {
  int idx = blockIdx.x * 256 + threadIdx.x;
  unsigned long long m = __ballot(adj[idx] > 0);
  if ((threadIdx.x & 63) == 0) {
    bits[idx >> 5]       = (uint32_t)m;
    bits[(idx >> 5) + 1] = (uint32_t)(m >> 32);
  }
}

// ------------------------------------------------- convert params + x to bf16
__global__ __launch_bounds__(256) void k_cvt(const float* __restrict__ x,
                                             const float* __restrict__ W1,
                                             const float* __restrict__ lin1,
                                             const float* __restrict__ res1,
                                             const float* __restrict__ W2,
                                             const float* __restrict__ lin2,
                                             const float* __restrict__ res2,
                                             bf16* __restrict__ xb,
                                             bf16* __restrict__ W1T,
                                             bf16* __restrict__ lin1T,
                                             bf16* __restrict__ res1T,
                                             bf16* __restrict__ W2T,
                                             bf16* __restrict__ lin2T,
                                             bf16* __restrict__ res2T) {
  int t = blockIdx.y;
  int i = blockIdx.x * 256 + threadIdx.x;
  switch (t) {
    case 0:
      if (i < N * D0) xb[i] = __float2bfloat16(x[i]);
      break;
    case 1:
      if (i < HEADS * F1 * D0) { int k = i & 255; int ho = i >> 8; int h = ho >> 7, o = ho & 127;
        W1T[i] = __float2bfloat16(W1[((size_t)h * D0 + k) * F1 + o]); }
      break;
    case 2:
      if (i < F1 * HEADS * F1) { int k = i & 511; int o = i >> 9;
        lin1T[i] = __float2bfloat16(lin1[k * F1 + o]); }
      break;
    case 3:
      if (i < F1 * D0) { int k = i & 255; int o = i >> 8;
        res1T[i] = __float2bfloat16(res1[k * F1 + o]); }
      break;
    case 4:
      if (i < HEADS * F2 * F1) { int k = i & 127; int ho = i >> 7; int h = ho >> 6, o = ho & 63;
        W2T[i] = __float2bfloat16(W2[((size_t)h * F1 + k) * F2 + o]); }
      break;
    case 5:
      if (i < F2 * HEADS * F2) { int k = i & 255; int o = i >> 8;
        lin2T[i] = __float2bfloat16(lin2[k * F2 + o]); }
      break;
    case 6:
      if (i < F2 * F1) { int k = i & 127; int o = i >> 7;
        res2T[i] = __float2bfloat16(res2[k * F2 + o]); }
      break;
  }
}

// ------------------------------------------------- projection GEMM (MFMA), 16-row blocks
// Computes Wh and stores it in MFMA B-fragment-packed order:
// BP[h][ct][jt][q'][c15][e]  (j = graph node = MFMA k; col = feature)
// Also fuses src/dst GEMV via shfl + atomicAdd.
template <int K, int NOUT, int F>
__global__ __launch_bounds__(256) void k_whead_mfma(const bf16* __restrict__ A,
                                                    const bf16* __restrict__ BT,
                                                    bf16* __restrict__ BP,
                                                    const float* __restrict__ as_,
                                                    const float* __restrict__ ad_,
                                                    float* __restrict__ src,
                                                    float* __restrict__ dst) {
  int row0 = blockIdx.x * 16;
  int wid = threadIdx.x >> 6, lane = threadIdx.x & 63;
  int l15 = lane & 15, q = lane >> 4;
  int col = blockIdx.y * 64 + wid * 16 + l15;

  const bf16* aP = A + (size_t)(row0 + l15) * K + q * 8;
  const bf16* bP = BT + (size_t)col * K + q * 8;
  f32x4 acc;
#pragma unroll
  for (int r = 0; r < 4; r++) acc[r] = 0.f;
#pragma unroll
  for (int ks = 0; ks < K / 32; ks++) {
    short8 a = *(const short8*)(aP + ks * 32);
    short8 b = *(const short8*)(bP + ks * 32);
    acc = __builtin_amdgcn_mfma_f32_16x16x32_bf16(a, b, acc, 0, 0, 0);
  }

  // fragment-packed store: j=row0+q*4+r, jt=row0>>5, q'=half*2+(q>>1), e=(q&1)*4+r
  int h  = col / F;
  int cl = col % F;
  int ct = cl >> 4;
  int jt = row0 >> 5;
  int qp = ((row0 >> 4) & 1) * 2 + (q >> 1);
  int eo = (q & 1) * 4;
  short4v w;
#pragma unroll
  for (int r = 0; r < 4; r++) w[r] = f2bs(acc[r]);
  size_t off = ((((size_t)h * (F / 16) + ct) * (N / 32) + jt) * 4 + qp) * 128 + l15 * 8 + eo;
  *(short4v*)(BP + off) = w;

  float asv = as_[col], adv = ad_[col];
#pragma unroll
  for (int r = 0; r < 4; r++) {
    float sp = acc[r] * asv, dp = acc[r] * adv;
#pragma unroll
    for (int m = 1; m < 16; m <<= 1) {
      sp += __shfl_xor(sp, m);
      dp += __shfl_xor(dp, m);
    }
    if (l15 == 0) {
      atomicAdd(&src[h * N + row0 + q * 4 + r], sp);
      atomicAdd(&dst[h * N + row0 + q * 4 + r], dp);
    }
  }
}

// ---------------- fused attention, packed-B, K-split, no main-loop barriers
// block: 32 rows x 1 head x 1 k-half; 4 waves each own K/8 = 384 j's.
// Partial (unnormalized) PV and rowsum accumulate additively into f32 buffers.
template <int F>
__global__ __launch_bounds__(256, 2) void k_attn_fused(const bf16* __restrict__ BP,
                                                       const float* __restrict__ src,
                                                       const float* __restrict__ dst,
                                                       const uint32_t* __restrict__ bits,
                                                       float* __restrict__ hp_part,
                                                       float* __restrict__ rs_part) {
  constexpr int CT = F / 16;             // 8 / 4
  constexpr int CTN = CT / 4;            // 2 / 1
  constexpr int KSTEPS = 12;             // 384 j per wave
  int h    = blockIdx.y;
  int kb   = blockIdx.z;
  int row0 = blockIdx.x * 32;
  int tid = threadIdx.x, wid = tid >> 6, lane = tid & 63;
  int l15 = lane & 15, q = lane >> 4;
  int jbase = kb * (N / 2) + wid * 384;

  float src0 = src[h * N + row0 + l15];
  float src1 = src[h * N + row0 + 16 + l15];
  const float* dh = dst + h * N;
  const uint32_t* b0 = bits + (size_t)(row0 + l15) * NW;
  const uint32_t* b1 = bits + (size_t)(row0 + 16 + l15) * NW;
  const bf16* bph = BP + (size_t)h * CT * (N / 32) * 512;

  f32x4 acc0[CT], acc1[CT];
#pragma unroll
  for (int ct = 0; ct < CT; ct++)
#pragma unroll
    for (int r = 0; r < 4; r++) { acc0[ct][r] = 0.f; acc1[ct][r] = 0.f; }
  float rs0 = 0.f, rs1 = 0.f;

  for (int ks = 0; ks < KSTEPS; ks++) {
    int j0 = jbase + ks * 32;
    int jt = j0 >> 5;
    f32x4 dlo = *(const f32x4*)(dh + j0 + q * 8);
    f32x4 dhi = *(const f32x4*)(dh + j0 + q * 8 + 4);
    uint32_t m0 = (b0[jt] >> (q * 8)) & 0xffu;
    uint32_t m1 = (b1[jt] >> (q * 8)) & 0xffu;
    float pv0[8], pv1[8];
#pragma unroll
    for (int e = 0; e < 8; e++) {
      float d = e < 4 ? dlo[e] : dhi[e - 4];
      float t0 = src0 + d; t0 = fmaxf(t0, 0.2f * t0);
      float p0 = ((m0 >> e) & 1u) ? __expf(t0 - CSHIFT) : 0.f;
      rs0 += p0; pv0[e] = p0;
      float t1 = src1 + d; t1 = fmaxf(t1, 0.2f * t1);
      float p1 = ((m1 >> e) & 1u) ? __expf(t1 - CSHIFT) : 0.f;
      rs1 += p1; pv1[e] = p1;
    }
    short8 a0, a1;
#pragma unroll
    for (int e = 0; e < 8; e++) { a0[e] = f2bs(pv0[e]); a1[e] = f2bs(pv1[e]); }
#pragma unroll
    for (int ct = 0; ct < CT; ct++) {
      short8 b = *(const short8*)(bph + (((size_t)ct * (N / 32) + jt) * 64 + lane) * 8);
      acc0[ct] = __builtin_amdgcn_mfma_f32_16x16x32_bf16(a0, b, acc0[ct], 0, 0, 0);
      acc1[ct] = __builtin_amdgcn_mfma_f32_16x16x32_bf16(a1, b, acc1[ct], 0, 0, 0);
    }
  }

  // row sums (this wave's j-range): combine q-slices -> all lanes hold row total
  rs0 += __shfl_xor(rs0, 16); rs0 += __shfl_xor(rs0, 32);
  rs1 += __shfl_xor(rs1, 16); rs1 += __shfl_xor(rs1, 32);
  if (q == 0) atomicAdd(&rs_part[((size_t)kb * HEADS + h) * N + row0 + l15], rs0);
  if (q == 1) atomicAdd(&rs_part[((size_t)kb * HEADS + h) * N + row0 + 16 + l15], rs1);

  // cross-wave accumulator reduction, 2 rounds (one per 16-row tile)
  __shared__ float red[4][64][CT * 4 + 1];
#pragma unroll
  for (int t = 0; t < 2; t++) {
    __syncthreads();
#pragma unroll
    for (int ct = 0; ct < CT; ct++)
#pragma unroll
      for (int r = 0; r < 4; r++)
        red[wid][lane][ct * 4 + r] = t ? acc1[ct][r] : acc0[ct][r];
    __syncthreads();
#pragma unroll
    for (int cc = 0; cc < CTN; cc++) {
      int ct = wid * CTN + cc;
#pragma unroll
      for (int r = 0; r < 4; r++) {
        float v = red[0][lane][ct * 4 + r] + red[1][lane][ct * 4 + r] +
                  red[2][lane][ct * 4 + r] + red[3][lane][ct * 4 + r];
        int row = row0 + t * 16 + q * 4 + r;
        hp_part[((size_t)kb * N + row) * (HEADS * F) + h * F + ct * 16 + l15] = v;
      }
    }
  }
}

// ---------------- combine k-half partials: hp = elu((p0+p1)/(s0+s1)), bf16
template <int F>
__global__ __launch_bounds__(256) void k_attn_combine(const float* __restrict__ hp_part,
                                                      const float* __restrict__ rs_part,
                                                      bf16* __restrict__ hp) {
  constexpr int HF = HEADS * F;
  int i = (blockIdx.x * 256 + threadIdx.x) * 4;
  int row = i / HF, c = i % HF, h = c / F;
  f32x4 p0 = *(const f32x4*)(hp_part + (size_t)row * HF + c);
  f32x4 p1 = *(const f32x4*)(hp_part + ((size_t)N + row) * HF + c);
  float s = rs_part[h * N + row] + rs_part[(HEADS + h) * N + row];
  float inv = 1.f / s;
  short4v o;
#pragma unroll
  for (int r = 0; r < 4; r++) {
    float v = (p0[r] + p1[r]) * inv;
    v = v > 0.f ? v : __expf(v) - 1.f;   // elu
    o[r] = f2bs(v);
  }
  *(short4v*)(hp + i) = o;
}

// ------------------ mix GEMM (MFMA), 16-row blocks: out = relu(elu(A1@B1)+A2@B2)
template <int K1, int K2, int NOUT, bool F32OUT>
__global__ __launch_bounds__(256) void k_mix_mfma(const bf16* __restrict__ A1,
                                                  const bf16* __restrict__ B1T,
                                                  const bf16* __restrict__ A2,
                                                  const bf16* __restrict__ B2T,
                                                  void* __restrict__ outv) {
  int row0 = blockIdx.x * 16;
  int wid = threadIdx.x >> 6, lane = threadIdx.x & 63;
  int l15 = lane & 15, q = lane >> 4;
  int col = blockIdx.y * 64 + wid * 16 + l15;

  f32x4 acc1, acc2;
#pragma unroll
  for (int r = 0; r < 4; r++) { acc1[r] = 0.f; acc2[r] = 0.f; }

  const bf16* a1P = A1 + (size_t)(row0 + l15) * K1 + q * 8;
  const bf16* b1P = B1T + (size_t)col * K1 + q * 8;
#pragma unroll
  for (int ks = 0; ks < K1 / 32; ks++) {
    short8 a = *(const short8*)(a1P + ks * 32);
    short8 b = *(const short8*)(b1P + ks * 32);
    acc1 = __builtin_amdgcn_mfma_f32_16x16x32_bf16(a, b, acc1, 0, 0, 0);
  }
  const bf16* a2P = A2 + (size_t)(row0 + l15) * K2 + q * 8;
  const bf16* b2P = B2T + (size_t)col * K2 + q * 8;
#pragma unroll
  for (int ks = 0; ks < K2 / 32; ks++) {
    short8 a = *(const short8*)(a2P + ks * 32);
    short8 b = *(const short8*)(b2P + ks * 32);
    acc2 = __builtin_amdgcn_mfma_f32_16x16x32_bf16(a, b, acc2, 0, 0, 0);
  }

#pragma unroll
  for (int r = 0; r < 4; r++) {
    float v = acc1[r];
    v = v > 0.f ? v : __expf(v) - 1.f;         // elu on A1@B1
    v += acc2[r];
    v = v > 0.f ? v : 0.f;                     // relu
    int rw = row0 + q * 4 + r;
    if (F32OUT) ((float*)outv)[(size_t)rw * NOUT + col] = v;
    else        ((bf16*)outv)[(size_t)rw * NOUT + col] = __float2bfloat16(v);
  }
}

// ---------------------------------------------------------------- launcher
extern "C" void kernel_launch(void* const* d_in, const int* in_sizes, int n_in,
                              void* d_out, int out_size, void* d_ws, size_t ws_size,
                              hipStream_t stream) {
  const float* x    = (const float*)d_in[0];
  const int*   adj  = (const int*)d_in[1];
  const float* W1   = (const float*)d_in[2];
  const float* a1s  = (const float*)d_in[3];
  const float* a1d  = (const float*)d_in[4];
  const float* lin1 = (const float*)d_in[5];
  const float* res1 = (const float*)d_in[6];
  const float* W2   = (const float*)d_in[7];
  const float* a2s  = (const float*)d_in[8];
  const float* a2d  = (const float*)d_in[9];
  const float* lin2 = (const float*)d_in[10];
  const float* res2 = (const float*)d_in[11];
  float* out = (float*)d_out;

  char* p = (char*)d_ws;
  auto alloc = [&](size_t bytes) { void* r = (void*)p; p += (bytes + 255) & ~(size_t)255; return r; };
  uint32_t* bits = (uint32_t*)alloc((size_t)N * NW * 4);
  bf16* xb    = (bf16*)alloc((size_t)N * D0 * 2);
  bf16* W1T   = (bf16*)alloc((size_t)HEADS * F1 * D0 * 2);
  bf16* lin1T = (bf16*)alloc((size_t)F1 * HEADS * F1 * 2);
  bf16* res1T = (bf16*)alloc((size_t)F1 * D0 * 2);
  bf16* W2T   = (bf16*)alloc((size_t)HEADS * F2 * F1 * 2);
  bf16* lin2T = (bf16*)alloc((size_t)F2 * HEADS * F2 * 2);
  bf16* res2T = (bf16*)alloc((size_t)F2 * F1 * 2);
  bf16* BP1   = (bf16*)alloc((size_t)HEADS * F1 * N * 2);   // fragment-packed Wh
  bf16* BP2   = (bf16*)alloc((size_t)HEADS * F2 * N * 2);
  // zeroed region: src1,dst1,src2,dst2,rs1,rs2 (contiguous)
  float* src1 = (float*)alloc((size_t)HEADS * N * 4);
  float* dst1 = (float*)alloc((size_t)HEADS * N * 4);
  float* src2 = (float*)alloc((size_t)HEADS * N * 4);
  float* dst2 = (float*)alloc((size_t)HEADS * N * 4);
  float* rs1  = (float*)alloc((size_t)2 * HEADS * N * 4);
  float* rs2  = (float*)alloc((size_t)2 * HEADS * N * 4);
  float* hpp1 = (float*)alloc((size_t)2 * N * HEADS * F1 * 4);
  float* hpp2 = (float*)alloc((size_t)2 * N * HEADS * F2 * 4);
  bf16* hp1   = (bf16*)alloc((size_t)N * HEADS * F1 * 2);
  bf16* hp2   = (bf16*)alloc((size_t)N * HEADS * F2 * 2);
  bf16* h1b   = (bf16*)alloc((size_t)N * F1 * 2);

  hipMemsetAsync(src1, 0, (size_t)HEADS * N * 4 * 8, stream);  // src/dst x2 + rs x2

  k_pack_adj<<<dim3(N * N / 256), dim3(256), 0, stream>>>(adj, bits);
  k_cvt<<<dim3(N * D0 / 256, 7), dim3(256), 0, stream>>>(x, W1, lin1, res1, W2, lin2, res2,
                                                         xb, W1T, lin1T, res1T, W2T, lin2T, res2T);

  // layer 1
  k_whead_mfma<D0, HEADS * F1, F1>
      <<<dim3(N / 16, HEADS * F1 / 64), dim3(256), 0, stream>>>(xb, W1T, BP1, a1s, a1d, src1, dst1);
  k_attn_fused<F1><<<dim3(N / 32, HEADS, 2), dim3(256), 0, stream>>>(BP1, src1, dst1, bits, hpp1, rs1);
  k_attn_combine<F1><<<dim3(N * HEADS * F1 / 1024), dim3(256), 0, stream>>>(hpp1, rs1, hp1);
  k_mix_mfma<HEADS * F1, D0, F1, false>
      <<<dim3(N / 16, F1 / 64), dim3(256), 0, stream>>>(hp1, lin1T, xb, res1T, h1b);

  // layer 2
  k_whead_mfma<F1, HEADS * F2, F2>
      <<<dim3(N / 16, HEADS * F2 / 64), dim3(256), 0, stream>>>(h1b, W2T, BP2, a2s, a2d, src2, dst2);
  k_attn_fused<F2><<<dim3(N / 32, HEADS, 2), dim3(256), 0, stream>>>(BP2, src2, dst2, bits, hpp2, rs2);
  k_attn_combine<F2><<<dim3(N * HEADS * F2 / 1024), dim3(256), 0, stream>>>(hpp2, rs2, hp2);
  k_mix_mfma<HEADS * F2, F1, F2, true>
      <<<dim3(N / 16, F2 / 64), dim3(256), 0, stream>>>(hp2, lin2T, h1b, res2T, out);
}